// Round 6
// baseline (479.498 us; speedup 1.0000x reference)
//
#include <hip/hip_runtime.h>
#include <hip/hip_bf16.h>
#include <math.h>

#define BB 4096
#define TT 48
#define FF 64
#define HH 128
#define ROWS 16
#define NT 512
#define NBLK (BB / ROWS)   // 256

typedef __attribute__((ext_vector_type(8))) short short8;
typedef __attribute__((ext_vector_type(4))) float f32x4;

__device__ __forceinline__ float sigm(float x) { return 1.f / (1.f + __expf(-x)); }
__device__ __forceinline__ float tanh_f(float x) { return 2.f / (1.f + __expf(-2.f * x)) - 1.f; }
// order-proof single f32 -> e4m3 byte (both packed bytes are cvt(x))
__device__ __forceinline__ unsigned int f32_to_e4m3(float x) {
    return (unsigned int)(__builtin_amdgcn_cvt_pk_fp8_f32(x, x, 0, false) & 0xff);
}

// ---- prep: Wcat as fp8 B-frags (ulong/lane) ; DH,H,F,C as bf16 B-frags ----
// frag flat per region: ((tile*KS + ks)*64 + lane)*8 + jj ;
//   n = tile*16+(lane&15), k = ks*32+(lane>>4)*8+jj
// wcat8: ulong[16384] (32 tiles x 8 ks). fbf bf16: DH@0 (els 0..8192),
// H@8192, F@16384 (diag zero), C@20480 ; total 28672 els.
__global__ __launch_bounds__(256) void prep_kernel(
    const float* __restrict__ W_ih, const float* __restrict__ W_hh,
    const float* __restrict__ Wdh,  const float* __restrict__ Wh,
    const float* __restrict__ Wf,   const float* __restrict__ Wc,
    unsigned long long* __restrict__ wcat8, __hip_bfloat16* __restrict__ fbf) {
    const int u = blockIdx.x * 256 + threadIdx.x;  // < 19968
    if (u < 16384) {
        const int lane = u & 63, ks = (u >> 6) & 7, tile = u >> 9;
        const int n = tile * 16 + (lane & 15);
        const int kb = ks * 32 + ((lane >> 4) << 3);
        const float* src = (kb < 128) ? (W_ih + n * 128 + kb)
                                      : (W_hh + n * 128 + kb - 128);
        unsigned int w0 = 0, w1 = 0;
        #pragma unroll
        for (int i = 0; i < 4; ++i) w0 |= f32_to_e4m3(src[i]) << (8 * i);
        #pragma unroll
        for (int i = 0; i < 4; ++i) w1 |= f32_to_e4m3(src[4 + i]) << (8 * i);
        wcat8[u] = ((unsigned long long)w1 << 32) | (unsigned long long)w0;
    } else {
        const int c = u - 16384;  // chunk of 8 els, < 3584
        const int lane = c & 63;
        const int lq = lane & 15, q8 = (lane >> 4) << 3;
        const float* src; int n, kb; bool fdiag = false;
        if (c < 1024) {                       // DH [128][64] KS=2
            const int ks = (c >> 6) & 1, tile = c >> 7;
            n = tile * 16 + lq; kb = ks * 32 + q8; src = Wdh + n * 64 + kb;
        } else if (c < 2048) {                // H [64][128] KS=4
            const int cc = c - 1024;
            const int ks = (cc >> 6) & 3, tile = cc >> 8;
            n = tile * 16 + lq; kb = ks * 32 + q8; src = Wh + n * 128 + kb;
        } else if (c < 2560) {                // F [64][64] KS=2, diag zero
            const int cc = c - 2048;
            const int ks = (cc >> 6) & 1, tile = cc >> 7;
            n = tile * 16 + lq; kb = ks * 32 + q8; src = Wf + n * 64 + kb;
            fdiag = true;
        } else {                              // C [64][128] KS=4
            const int cc = c - 2560;
            const int ks = (cc >> 6) & 3, tile = cc >> 8;
            n = tile * 16 + lq; kb = ks * 32 + q8; src = Wc + n * 128 + kb;
        }
        short8 out;
        #pragma unroll
        for (int i = 0; i < 8; ++i) {
            float v = src[i];
            if (fdiag && (kb + i == n)) v = 0.f;
            __hip_bfloat16 b = __float2bfloat16(v);
            out[i] = *(short*)&b;
        }
        *(short8*)(fbf + (size_t)(c) * 8) = out;  // c*8 == global el offset
    }
}

// ---- Main persistent kernel: block = 16 batch rows, 8 waves, 1 block/CU ----
__global__ __launch_bounds__(NT, 2) void rits_kernel(
    const float* __restrict__ values, const float* __restrict__ masks,
    const float* __restrict__ deltas,
    const float* __restrict__ Wdx, const float* __restrict__ bdx,
    const float* __restrict__ bdh, const float* __restrict__ bh,
    const float* __restrict__ bf,  const float* __restrict__ bc,
    const float* __restrict__ b_ih, const float* __restrict__ b_hh,
    const float* __restrict__ Wo,  const float* __restrict__ bo,
    const unsigned long long* __restrict__ wcat8,
    const __hip_bfloat16* __restrict__ fbf,
    float* __restrict__ ws_msum,   // [TT][NBLK][8]
    float* __restrict__ ws_numer,  // [TT][NBLK][4]
    float* __restrict__ out_imp, float* __restrict__ out_pred)
{
    __shared__ __align__(16) __hip_bfloat16 dbuf[ROWS][72];
    __shared__ __align__(16) __hip_bfloat16 xcbuf[ROWS][72];
    __shared__ __align__(16) __hip_bfloat16 hbuf16[ROWS][136];
    __shared__ __align__(16) unsigned char  hbuf8[ROWS][136];
    __shared__ __align__(16) unsigned char  ccm8[ROWS][136];
    __shared__ __align__(16) __hip_bfloat16 gxm[ROWS][136];
    __shared__ float x_lds[ROWS][65];
    __shared__ float m_lds[ROWS][65];
    __shared__ float alpha_buf[ROWS][68];
    // F (4096 els) and C (8192 els) in ONE array — adjacency guaranteed.
    // (R5 bug: separate F_lds/C_lds arrays + one staging loop overflowed
    //  F_lds into unrelated LDS buffers -> NaN.)
    __shared__ __align__(16) __hip_bfloat16 FC_lds[12288];

    const int tid = threadIdx.x;
    const int bid = blockIdx.x;
    const int b0 = bid * ROWS;
    const int lane = tid & 63;
    const int wv = tid >> 6;        // 0..7
    const int quad = lane >> 4;
    const int lq = lane & 15;

    // one-time: cache F,C B-frags in LDS (bf16)
    for (int i = tid; i < 12288 / 8; i += NT) {
        *(short8*)(FC_lds + i * 8) = *(const short8*)(fbf + 16384 + (size_t)i * 8);
    }

    const float wdx_l = Wdx[lane * (FF + 1)];
    const float bdx_l = bdx[lane];

    const int j_ln = wv * 16 + lq;      // ph3 / ph7 gate column
    const float bdh_j = bdh[j_ln];
    const float bI = b_ih[j_ln]       + b_hh[j_ln];
    const float bF = b_ih[128 + j_ln] + b_hh[128 + j_ln];
    const float bG = b_ih[256 + j_ln] + b_hh[256 + j_ln];
    const float bO = b_ih[384 + j_ln] + b_hh[384 + j_ln];

    const int f46 = (wv & 3) * 16 + lq; // ph4/5/6 feature column
    const float bh_f = bh[f46];
    const float bf_f = bf[f46];
    const float bc_f = bc[f46];

    float h_reg[4], c_reg[4];
    #pragma unroll
    for (int r = 0; r < 4; ++r) { h_reg[r] = 0.f; c_reg[r] = 0.f; }

    // preload inputs for t=0
    float xv_pf[2], mv_pf[2], dv_pf[2];
    #pragma unroll
    for (int q = 0; q < 2; ++q) {
        const int off = ((b0 + wv + 8 * q) * TT + 0) * FF + lane;
        xv_pf[q] = values[off]; mv_pf[q] = masks[off]; dv_pf[q] = deltas[off];
    }
    __syncthreads();

    for (int t = 0; t < TT; ++t) {
        // ---- p1: issue DH/H B-loads ; stage inputs ; mask partial ----
        short8 bDH[2];
        #pragma unroll
        for (int ks = 0; ks < 2; ++ks)
            bDH[ks] = *(const short8*)(fbf + (size_t)((((wv * 2 + ks) << 6) + lane)) * 8);
        short8 bH[4];
        if (wv < 4) {
            #pragma unroll
            for (int ks = 0; ks < 4; ++ks)
                bH[ks] = *(const short8*)(fbf + 8192 + (size_t)(((((wv & 3) * 4 + ks) << 6) + lane)) * 8);
        }
        float msum_th = 0.f;
        #pragma unroll
        for (int q = 0; q < 2; ++q) {
            const int r = wv + 8 * q;
            const float xv = xv_pf[q], mv = mv_pf[q], dv = dv_pf[q];
            x_lds[r][lane] = xv;
            m_lds[r][lane] = mv;
            msum_th += mv;
            dbuf[r][lane] = __float2bfloat16(dv);
            const float gx = __expf(-fmaxf(fmaf(dv, wdx_l, bdx_l), 0.f));
            gxm[r][lane] = __float2bfloat16(gx);
            gxm[r][64 + lane] = __float2bfloat16(mv);
        }
        #pragma unroll
        for (int off = 32; off; off >>= 1) msum_th += __shfl_down(msum_th, off, 64);
        __syncthreads();  // B1

        // ---- ph3: gamma_h (bf16 MFMA) ; decay h_reg ; publish h to LDS ----
        {
            f32x4 acc = {0.f, 0.f, 0.f, 0.f};
            #pragma unroll
            for (int ks = 0; ks < 2; ++ks) {
                const short8 a = *(const short8*)&dbuf[lq][ks * 32 + quad * 8];
                acc = __builtin_amdgcn_mfma_f32_16x16x32_bf16(a, bDH[ks], acc, 0, 0, 0);
            }
            #pragma unroll
            for (int r = 0; r < 4; ++r) {
                const int row = quad * 4 + r;
                const float gh = __expf(-fmaxf(acc[r] + bdh_j, 0.f));
                h_reg[r] *= gh;
                hbuf16[row][j_ln] = __float2bfloat16(h_reg[r]);
                hbuf8[row][j_ln] = (unsigned char)f32_to_e4m3(h_reg[r]);
            }
        }
        __syncthreads();  // B2

        // ---- ph4-region: prefetch Wcat B-frags ; x_h (w0-3) || alpha (w4-7) ----
        long wB[32];
        #pragma unroll
        for (int g = 0; g < 4; ++g)
            #pragma unroll
            for (int ks = 0; ks < 8; ++ks)
                wB[g * 8 + ks] = (long)wcat8[((((g * 8 + wv) * 8 + ks)) << 6) + lane];

        float xv_r[4], mv_r[4], xh_r[4];
        if (wv < 4) {
            f32x4 acc = {0.f, 0.f, 0.f, 0.f};
            #pragma unroll
            for (int ks = 0; ks < 4; ++ks) {
                const short8 a = *(const short8*)&hbuf16[lq][ks * 32 + quad * 8];
                acc = __builtin_amdgcn_mfma_f32_16x16x32_bf16(a, bH[ks], acc, 0, 0, 0);
            }
            #pragma unroll
            for (int r = 0; r < 4; ++r) {
                const int row = quad * 4 + r;
                const float xh = acc[r] + bh_f;
                xh_r[r] = xh;
                const float xv = x_lds[row][f46], mv = m_lds[row][f46];
                xv_r[r] = xv; mv_r[r] = mv;
                xcbuf[row][f46] = __float2bfloat16(fmaf(mv, xv, (1.f - mv) * xh));
            }
        } else {
            f32x4 acc = {0.f, 0.f, 0.f, 0.f};
            const int wv2 = wv - 4;
            #pragma unroll
            for (int ks = 0; ks < 4; ++ks) {
                const short8 a = *(const short8*)&gxm[lq][ks * 32 + quad * 8];
                const short8 b = *(const short8*)&FC_lds[4096 + (size_t)((((wv2 * 4 + ks) << 6) + lane)) * 8];
                acc = __builtin_amdgcn_mfma_f32_16x16x32_bf16(a, b, acc, 0, 0, 0);
            }
            #pragma unroll
            for (int r = 0; r < 4; ++r)
                alpha_buf[quad * 4 + r][f46] = acc[r] + bc_f;
        }
        __syncthreads();  // B3

        // ---- ph5: z_h (F cached) ; combine with alpha ; losses ; c_c ----
        float stepsum = 0.f;
        float cc_r[4];
        if (wv < 4) {
            f32x4 acc = {0.f, 0.f, 0.f, 0.f};
            #pragma unroll
            for (int ks = 0; ks < 2; ++ks) {
                const short8 a = *(const short8*)&xcbuf[lq][ks * 32 + quad * 8];
                const short8 b = *(const short8*)&FC_lds[(size_t)(((((wv & 3) * 2 + ks) << 6) + lane)) * 8];
                acc = __builtin_amdgcn_mfma_f32_16x16x32_bf16(a, b, acc, 0, 0, 0);
            }
            #pragma unroll
            for (int r = 0; r < 4; ++r) {
                const int row = quad * 4 + r;
                const float zh = acc[r] + bf_f;
                stepsum += mv_r[r] * fabsf(xv_r[r] - xh_r[r]);
                stepsum += mv_r[r] * fabsf(xv_r[r] - zh);
                const float alpha = alpha_buf[row][f46];
                const float ch = fmaf(alpha, zh, (1.f - alpha) * xh_r[r]);
                stepsum += mv_r[r] * fabsf(xv_r[r] - ch);
                const float cc = fmaf(mv_r[r], xv_r[r], (1.f - mv_r[r]) * ch);
                cc_r[r] = cc;
                ccm8[row][f46] = (unsigned char)f32_to_e4m3(cc);
                ccm8[row][64 + f46] = (unsigned char)f32_to_e4m3(mv_r[r]);
            }
            #pragma unroll
            for (int off = 32; off; off >>= 1) stepsum += __shfl_down(stepsum, off, 64);
        }
        __syncthreads();  // B4

        // ---- ph7-region: batched global ops + fp8 gates MFMA + LSTM ----
        if (lane == 0) ws_msum[(t * NBLK + bid) * 8 + wv] = msum_th;
        if (wv < 4) {
            if (lane == 0) ws_numer[(t * NBLK + bid) * 4 + wv] = stepsum;
            #pragma unroll
            for (int r = 0; r < 4; ++r) {
                const int row = quad * 4 + r;
                out_imp[((b0 + row) * TT + t) * FF + f46] = cc_r[r];
            }
        }
        const int tn = (t + 1 < TT) ? t + 1 : t;
        #pragma unroll
        for (int q = 0; q < 2; ++q) {
            const int off = ((b0 + wv + 8 * q) * TT + tn) * FF + lane;
            xv_pf[q] = values[off]; mv_pf[q] = masks[off]; dv_pf[q] = deltas[off];
        }
        {
            f32x4 acc7[4];
            #pragma unroll
            for (int g = 0; g < 4; ++g) acc7[g] = (f32x4){0.f, 0.f, 0.f, 0.f};
            #pragma unroll
            for (int ks = 0; ks < 8; ++ks) {
                const long a = (ks < 4)
                    ? *(const long*)&ccm8[lq][ks * 32 + quad * 8]
                    : *(const long*)&hbuf8[lq][(ks - 4) * 32 + quad * 8];
                #pragma unroll
                for (int g = 0; g < 4; ++g)
                    acc7[g] = __builtin_amdgcn_mfma_f32_16x16x32_fp8_fp8(a, wB[g * 8 + ks], acc7[g], 0, 0, 0);
            }
            #pragma unroll
            for (int r = 0; r < 4; ++r) {
                const float ig = sigm(acc7[0][r] + bI);
                const float fg = sigm(acc7[1][r] + bF);
                const float gg = tanh_f(acc7[2][r] + bG);
                const float og = sigm(acc7[3][r] + bO);
                c_reg[r] = fmaf(fg, c_reg[r], ig * gg);
                h_reg[r] = og * tanh_f(c_reg[r]);
            }
        }
        // no end-of-step barrier: hbuf/ccm written next step after B1/B3
    }

    // ---- predictions: publish final h, reduce h @ Wo.T + bo ----
    #pragma unroll
    for (int r = 0; r < 4; ++r)
        hbuf16[quad * 4 + r][j_ln] = __float2bfloat16(h_reg[r]);
    __syncthreads();
    {
        const int r = tid >> 5, l = tid & 31;
        float s = 0.f;
        #pragma unroll
        for (int k = l; k < HH; k += 32) s += __bfloat162float(hbuf16[r][k]) * Wo[k];
        #pragma unroll
        for (int off = 16; off; off >>= 1) s += __shfl_down(s, off, 32);
        if (l == 0) out_pred[b0 + r] = s + bo[0];
    }
}

// ---- final: loss = sum_t numer_t / (msum_t + 1e-5) ----
__global__ __launch_bounds__(256) void final_kernel(const float* __restrict__ ws_msum,
                                                    const float* __restrict__ ws_numer,
                                                    float* __restrict__ out_loss) {
    const int tid = threadIdx.x;
    const int lane = tid & 63, wvf = tid >> 6;
    __shared__ float red[4];
    float acc = 0.f;
    for (int t = wvf; t < TT; t += 4) {
        float ms = 0.f, ns = 0.f;
        for (int i = lane; i < NBLK * 8; i += 64) ms += ws_msum[t * NBLK * 8 + i];
        for (int i = lane; i < NBLK * 4; i += 64) ns += ws_numer[t * NBLK * 4 + i];
        #pragma unroll
        for (int off = 32; off; off >>= 1) {
            ms += __shfl_down(ms, off, 64);
            ns += __shfl_down(ns, off, 64);
        }
        if (lane == 0) acc += ns / (ms + 1e-5f);
    }
    if (lane == 0) red[wvf] = acc;
    __syncthreads();
    if (tid == 0) out_loss[0] = red[0] + red[1] + red[2] + red[3];
}

extern "C" void kernel_launch(void* const* d_in, const int* in_sizes, int n_in,
                              void* d_out, int out_size, void* d_ws, size_t ws_size,
                              hipStream_t stream) {
    const float* values = (const float*)d_in[0];
    const float* masks  = (const float*)d_in[1];
    const float* deltas = (const float*)d_in[2];
    const float* Wdh  = (const float*)d_in[3];
    const float* bdh  = (const float*)d_in[4];
    const float* Wdx  = (const float*)d_in[5];
    const float* bdx  = (const float*)d_in[6];
    const float* Wh   = (const float*)d_in[7];
    const float* bh   = (const float*)d_in[8];
    const float* Wf   = (const float*)d_in[9];
    const float* bf   = (const float*)d_in[10];
    const float* Wc   = (const float*)d_in[11];
    const float* bc   = (const float*)d_in[12];
    const float* W_ih = (const float*)d_in[13];
    const float* W_hh = (const float*)d_in[14];
    const float* b_ih = (const float*)d_in[15];
    const float* b_hh = (const float*)d_in[16];
    const float* Wo   = (const float*)d_in[17];
    const float* bo   = (const float*)d_in[18];

    unsigned long long* wcat8 = (unsigned long long*)d_ws;            // 131072 B
    __hip_bfloat16* fbf = (__hip_bfloat16*)((char*)d_ws + 131072);    // 57344 B
    float* ws_msum  = (float*)((char*)d_ws + 188416);                 // 48*256*8 f32
    float* ws_numer = (float*)((char*)d_ws + 581632);                 // 48*256*4 f32

    float* out_loss = (float*)d_out;
    float* out_imp  = out_loss + 1;
    float* out_pred = out_imp + (size_t)BB * TT * FF;

    prep_kernel<<<78, 256, 0, stream>>>(W_ih, W_hh, Wdh, Wh, Wf, Wc, wcat8, fbf);
    rits_kernel<<<NBLK, NT, 0, stream>>>(
        values, masks, deltas, Wdx, bdx, bdh, bh, bf, bc,
        b_ih, b_hh, Wo, bo, wcat8, fbf, ws_msum, ws_numer, out_imp, out_pred);
    final_kernel<<<1, 256, 0, stream>>>(ws_msum, ws_numer, out_loss);
}